// Round 20
// baseline (157.804 us; speedup 1.0000x reference)
//
#include <hip/hip_runtime.h>

typedef unsigned short u16;
typedef unsigned int   u32;
typedef __attribute__((ext_vector_type(4))) short s4;
typedef __attribute__((ext_vector_type(8))) short s8;
typedef __attribute__((ext_vector_type(4))) float f4;
typedef __attribute__((ext_vector_type(16))) float f16v;

#define NB   8
#define SEQ  1025
#define DIM  768
#define NH   12
#define HD   64
#define BPAD 1040      // rows per batch, padded (65*16)
#define MPAD 8320      // 8*1040
#define MV   8200      // valid rows for gemm2
#define SQP  1040      // Q rows per (b,h)
#define SKP  1088      // K rows per (b,h): 17*64
#define NG16 68        // kv 16-groups per (b,h)
#define NQKV 2304
#define BHT  96
// hd^-0.5 * log2(e) folded into Q (softmax uses exp2)
#define QSCALE 0.1803368801111204f

__device__ __forceinline__ u16 f2bf(float f) {
  u32 u = __builtin_bit_cast(u32, f);
  u += 0x7fffu + ((u >> 16) & 1u);
  return (u16)(u >> 16);
}
__device__ __forceinline__ float bf2f(u16 h) {
  return __builtin_bit_cast(float, ((u32)h) << 16);
}
__device__ __forceinline__ float exp2f_(float x) {
#if __has_builtin(__builtin_amdgcn_exp2f)
  return __builtin_amdgcn_exp2f(x);
#else
  return exp2f(x);
#endif
}
__device__ __forceinline__ u32 cvtpk(float a, float b) {
  u32 r;
  asm("v_cvt_pk_bf16_f32 %0, %1, %2" : "=v"(r) : "v"(a), "v"(b));
  return r;
}

typedef const __attribute__((address_space(1))) void cas1v;
typedef __attribute__((address_space(3))) void as3v;
__device__ __forceinline__ void gload16(const void* g, void* l) {
  __builtin_amdgcn_global_load_lds((cas1v*)g, (as3v*)l, 16, 0, 0);
}

#define MFMA16(a, b, c) __builtin_amdgcn_mfma_f32_16x16x32_bf16(a, b, c, 0, 0, 0)
#define MFMA32(a, b, c) __builtin_amdgcn_mfma_f32_32x32x16_bf16(a, b, c, 0, 0, 0)

// ---- fused conversions: x (batch-padded bf16), weights, qkv bias, RoPE table ----
__global__ void conv_all(const float* __restrict__ x,
                         const float* __restrict__ qw, const float* __restrict__ kw,
                         const float* __restrict__ vw, const float* __restrict__ ow,
                         const float* __restrict__ qb, const float* __restrict__ vb,
                         u16* __restrict__ xb,
                         u16* __restrict__ wqkv, u16* __restrict__ wo,
                         float* __restrict__ biasq, float2* __restrict__ rt) {
  if (blockIdx.x < 6240) {                        // ---- x part: 8320*768/4 elems ----
    int i = blockIdx.x * 256 + threadIdx.x;
    int e = i * 4;
    int row = e / DIM, col = e - row * DIM;
    int b = row / BPAD, s = row - b * BPAD;
    s4 o;
    if (s < SEQ) {
      float4 v = *(const float4*)(x + ((size_t)(b * SEQ + s)) * DIM + col);
      o[0] = (short)f2bf(v.x); o[1] = (short)f2bf(v.y);
      o[2] = (short)f2bf(v.z); o[3] = (short)f2bf(v.w);
    } else {
      o = (s4){0, 0, 0, 0};
    }
    *(s4*)(xb + e) = o;
  } else {                                        // ---- weights part: 589,824 elems ----
    int i = (blockIdx.x - 6240) * 256 + threadIdx.x;
    wqkv[i]           = f2bf(qw[i]);
    wqkv[i + 589824]  = f2bf(kw[i]);
    wqkv[i + 1179648] = f2bf(vw[i]);
    wo[i]             = f2bf(ow[i]);
    if (i < NQKV) biasq[i] = (i < 768) ? qb[i] : (i < 1536 ? 0.f : vb[i - 1536]);
    if (i < SEQ * 32) {                           // rope table rt[s][jj]
      int s = i >> 5, jj = i & 31;
      float cs = 1.f, sn = 0.f;
      if (s > 0) {
        int tok = s - 1;
        int pos = (jj < 16) ? (tok >> 5) : (tok & 31);
        int f = jj & 15;
        float ang = (float)pos * __expf((float)f * -0.28782313662425572f); // 100^(-f/16)
        __sincosf(ang, &sn, &cs);
      }
      rt[i] = make_float2(cs, sn);
    }
  }
}

// ======== gemm_qkv: 128m x 256n tile, BK=32, PAIRED K-steps (4 buffers, 96KB LDS) ========
// 8 waves = 2m x 4n, 64x64 each (acc[4][4]). Stage a PAIR of K-steps, compute a pair,
// ONE __syncthreads per pair -> 12 barrier/drain events instead of 24 (mechanism validated
// on attn in r18/r19). Epilogue: two 64-row halves through a 64x258 C-tile (aliases LDS).
__global__ __launch_bounds__(512) void gemm_qkv(const u16* __restrict__ A, const u16* __restrict__ Bm,
                                                const float* __restrict__ bias,
                                                u16* __restrict__ Ql, u16* __restrict__ Kl,
                                                u16* __restrict__ Vp, const float2* __restrict__ rt) {
  __shared__ u16 smem[49152];            // A bufs 0..3 @ [0,16384); B bufs 0..3 @ [16384,49152)
  const int K = DIM;
  int tid = threadIdx.x;
  int lane = tid & 63, wave = tid >> 6;
  int g = lane >> 4, c16 = lane & 15;
  int wm = wave >> 2, wn = wave & 3;
  // bijective XCD swizzle (m204), n fastest
  int nwg = gridDim.x, orig = blockIdx.x;
  int qd = nwg >> 3, rm = nwg & 7, xcd = orig & 7;
  int wgid = (xcd < rm ? xcd * (qd + 1) : rm * (qd + 1) + (xcd - rm) * qd) + (orig >> 3);
  int m0 = (wgid / 9) * 128, n0 = (wgid % 9) * 256;
  f4 acc[4][4] = {};

  int ldrow = wave * 16 + (lane >> 2);               // 0..127
  int ldk = ((lane & 3) ^ ((ldrow >> 1) & 3)) * 8;   // inverse chunk swizzle on global source
  const u16* Asrc = A + (size_t)(m0 + ldrow) * K + ldk;
  const u16* Bsrc = Bm + (size_t)(n0 + ldrow) * K + ldk;

  auto stage = [&](int buf, int k0) {
    gload16(Asrc + k0,           smem + buf * 4096 + wave * 512);                    // A 128x32
    gload16(Bsrc + k0,           smem + 16384 + buf * 8192 + wave * 512);            // B rows 0..127
    gload16(Bsrc + 128 * K + k0, smem + 16384 + buf * 8192 + 4096 + wave * 512);     // B rows 128..255
  };

  int kx = (g ^ ((c16 >> 1) & 3)) * 8;               // swizzled read chunk

  auto kstep = [&](int buf) {
    s8 af[4], bf[4];
#pragma unroll
    for (int i = 0; i < 4; i++) {
      af[i] = *(const s8*)(smem + buf * 4096 + (wm * 64 + i * 16 + c16) * 32 + kx);
      bf[i] = *(const s8*)(smem + 16384 + buf * 8192 + (wn * 64 + i * 16 + c16) * 32 + kx);
    }
    __builtin_amdgcn_s_setprio(1);
#pragma unroll
    for (int i = 0; i < 4; i++)
#pragma unroll
      for (int j = 0; j < 4; j++)
        acc[i][j] = MFMA16(af[i], bf[j], acc[i][j]);
    __builtin_amdgcn_s_setprio(0);
  };

  // prologue: stage pair 0 (K-steps 0,1) into bufs 0,1
  stage(0, 0);
  stage(1, 32);
  __syncthreads();

  for (int p = 0; p < 12; p++) {       // 12 pairs cover K-steps 0..23
    int base = (p & 1) << 1;           // bufs {base, base+1} hold this pair
    int nbase = base ^ 2;
    if (p < 11) {
      stage(nbase,     (2 * p + 2) << 5);
      stage(nbase + 1, (2 * p + 3) << 5);
    }
    kstep(base);
    kstep(base + 1);
    __syncthreads();                   // drains next-pair gloads + this pair's ds_reads
  }

  // ======== epilogue: two 64-row halves through a 64x258 C-tile (33KB, aliases LDS) ====
  int part = (n0 >= 1536) ? 2 : (n0 >= 768 ? 1 : 0);   // 256-blocks are part-pure
  float qs = (part == 0) ? QSCALE : 1.0f;
  u16 (*ct)[258] = (u16(*)[258])smem;
#pragma unroll
  for (int ih = 0; ih < 2; ih++) {
    __syncthreads();                     // prior reads of ct/staging complete
#pragma unroll
    for (int j = 0; j < 4; j++) {
      int col = wn * 64 + j * 16 + c16;                // 0..255
      float bv = bias[n0 + col];
      int jj = (col & 63) >> 1;
      int odd = col & 1;
#pragma unroll
      for (int il = 0; il < 2; il++) {
        int i = ih * 2 + il;
        int lrow = wm * 32 + il * 16 + g * 4;          // local C-tile row base
        int mrow = m0 + wm * 64 + i * 16 + g * 4;      // global m base
#pragma unroll
        for (int r = 0; r < 4; r++) {
          float v = acc[i][j][r] + bv;
          u16 o;
          if (part < 2) {
            float vp = __shfl_xor(v, 1);
            int s = (mrow + r) % BPAD;
            float2 t = rt[(s < SEQ ? s : SEQ - 1) * 32 + jj];
            float rv = odd ? (v * t.x + vp * t.y) : (v * t.x - vp * t.y);
            o = f2bf(rv * qs);
          } else {
            o = f2bf(v);
          }
          ct[lrow + r][col] = o;
        }
      }
    }
    __syncthreads();
    if (part < 2) {
      u16* dstB = (part == 0) ? Ql : Kl;
      int stride = (part == 0) ? SQP : SKP;
#pragma unroll
      for (int p = 0; p < 4; p++) {
        int task = p * 512 + tid;        // 2048 tasks: 64 rows x 32 col-groups
        int lrow = task >> 5, cg = (task & 31) * 8;
        int m = m0 + (lrow >> 5) * 64 + ih * 32 + (lrow & 31);
        int b = m / BPAD, s = m - b * BPAD;
        int n = n0 + cg;
        int hq = (n >> 6) - part * NH;
        s8 v = *(const s8*)&ct[lrow][cg];
        *(s8*)(dstB + ((size_t)((b * NH + hq) * stride + s)) * HD + (n & 63)) = v;
      }
    } else {
#pragma unroll
      for (int p = 0; p < 2; p++) {
        int task = p * 512 + tid;        // 1024 tasks: 4 strips x 256 cols
        int col = task & 255, rg = task >> 8;
        int lbase = rg * 16;
        int mb = m0 + (lbase >> 5) * 64 + ih * 32 + (lbase & 31);
        int b = mb / BPAD, sb = mb - b * BPAD;
        int g16 = sb >> 4;               // 16-strip aligned, batch-pure (1040 % 16 == 0)
        int n = n0 + col;
        int hq = (n >> 6) - 2 * NH;
        s8 o0, o1;
#pragma unroll
        for (int k = 0; k < 16; k++) {
          int mp = (k & 3) | (((k >> 3) & 1) << 2) | (((k >> 2) & 1) << 3);
          u16 val = ct[lbase + k][col];
          if (mp < 8) o0[mp] = (short)val; else o1[mp - 8] = (short)val;
        }
        u16* dst = Vp + ((size_t)((b * NH + hq) * NG16 + g16) * HD + (n & 63)) * 16;
        *(s8*)dst = o0;
        *(s8*)(dst + 8) = o1;
      }
    }
  }
}

// ---------------- gemm_o: 128x128 tile, 2-phase dbuf (proven), f32 out + bias ----------------
__global__ __launch_bounds__(256) void gemm_o(const u16* __restrict__ A, const u16* __restrict__ Bm,
                                              float* __restrict__ Cf, const float* __restrict__ bias,
                                              int N, int K, int Mvalid, int nnt) {
  __shared__ u16 smem[16384];
  int tid = threadIdx.x;
  int lane = tid & 63, wave = tid >> 6;
  int g = lane >> 4, c16 = lane & 15;
  int nwg = gridDim.x, orig = blockIdx.x;
  int qd = nwg >> 3, rm = nwg & 7, xcd = orig & 7;
  int wgid = (xcd < rm ? xcd * (qd + 1) : rm * (qd + 1) + (xcd - rm) * qd) + (orig >> 3);
  int m0 = (wgid / nnt) * 128, n0 = (wgid % nnt) * 128;
  int wm = wave >> 1, wn = wave & 1;
  f4 acc[4][4] = {};

  int ldrow = wave * 16 + (lane >> 2);
  int ldk = ((lane & 3) ^ ((ldrow >> 1) & 3)) * 8;
  const u16* Asrc = A + (size_t)(m0 + ldrow) * K + ldk;
  const u16* Bsrc = Bm + (size_t)(n0 + ldrow) * K + ldk;

  auto stage = [&](int buf, int k0) {
    u16* aw = smem + buf * 4096 + wave * 512;
    u16* bw = smem + 8192 + buf * 4096 + wave * 512;
    gload16(Asrc + k0, aw);
    gload16(Asrc + 64 * K + k0, aw + 2048);
    gload16(Bsrc + k0, bw);
    gload16(Bsrc + 64 * K + k0, bw + 2048);
  };

  stage(0, 0);
  __syncthreads();
  int nk = K >> 5;
  int kx = (g ^ ((c16 >> 1) & 3)) * 8;
  for (int t = 0; t < nk; t++) {
    int buf = t & 1;
    if (t + 1 < nk) stage(buf ^ 1, (t + 1) << 5);
    s8 af[4], bf[4];
#pragma unroll
    for (int i = 0; i < 4; i++) {
      af[i] = *(const s8*)(smem + buf * 4096 + (wm * 64 + i * 16 + c16) * 32 + kx);
      bf[i] = *(const s8*)(smem + 8192 + buf * 4096 + (wn * 64 + i * 16 + c16) * 32 + kx);
    }
    __builtin_amdgcn_s_setprio(1);
#pragma unroll
    for (int i = 0; i < 4; i++)
#pragma unroll
      for (int j = 0; j < 4; j++)
        acc[i][j] = MFMA16(af[i], bf[j], acc[i][j]);
    __builtin_amdgcn_s_setprio(0);
    __syncthreads();
  }

#pragma unroll
  for (int i = 0; i < 4; i++)
#pragma unroll
    for (int j = 0; j < 4; j++) {
      int n = n0 + wn * 64 + j * 16 + c16;
      float bv = bias[n];
#pragma unroll
      for (int r = 0; r < 4; r++) {
        int m = m0 + wm * 64 + i * 16 + g * 4 + r;
        if (m < Mvalid) Cf[(size_t)m * N + n] = acc[i][j][r] + bv;
      }
    }
}

// ---------------- flash attention: 4 waves x 32 q-rows, KVBLK=64, PAIRED chunks ----------------
// K staged to LDS (XOR swizzle) with FOUR buffers: stage a PAIR of chunks, compute a pair,
// ONE __syncthreads per pair -> 9 barrier/drain events instead of 17. Tail chunk 16 is
// staged into buf 0 at p=7 and read from buf 0. V direct from global (Vp pre-permuted,
// coalesced b128). NO-MAX softmax (bounded scores).
__global__ __launch_bounds__(256) void attn_k(const u16* __restrict__ Q, const u16* __restrict__ K,
                                              const u16* __restrict__ Vp, u16* __restrict__ Ao) {
  __shared__ u16 lds[4][64 * 64];      // 4 x 8 KiB K tiles = 32 KiB
  int bh = blockIdx.x;
  int tid = threadIdx.x;
  int wave = tid >> 6, lane = tid & 63;
  int q32 = lane & 31, h = lane >> 5;
  int b = bh / NH, hh = bh % NH;
  int qb = blockIdx.y * 128 + wave * 32;
  if (qb > SEQ - 32) qb = SEQ - 32;    // tail waves recompute rows (identical writes)
  const u16* Qb = Q + (size_t)bh * SQP * HD;
  const u16* Kb = K + (size_t)bh * SKP * HD;
  const u16* Vb = Vp + (size_t)bh * NG16 * 1024 + 16 * q32 + 8 * h;  // lane-fixed offset

  s8 qf[4];
#pragma unroll
  for (int t = 0; t < 4; t++)
    qf[t] = *(const s8*)(Qb + (size_t)(qb + q32) * HD + 16 * t + 8 * h);

  f16v o0 = {}, o1 = {};
  float lrun = 0.f;
  int swz = (q32 & 7) << 4;

  auto stage = [&](int buf, int c) {   // K only: 2 x gload16 per thread
#pragma unroll
    for (int i = 0; i < 2; i++) {
      int sb = i * 4096 + tid * 16;
      int row = sb >> 7;
      int ch = (sb >> 4) & 7;
      int so = (ch ^ (row & 7)) * 8;
      u16* kd = &lds[buf][i * 2048 + wave * 512];
      gload16(Kb + (size_t)(c * 64 + row) * HD + so, kd);
    }
  };

  auto body = [&](int c, int buf, bool tail) {
    // V fragments: direct global b128, issued first (hidden under QK + softmax)
    s8 vf0[4], vf1[4];
    {
      const u16* vc = Vb + c * 4096;
#pragma unroll
      for (int s = 0; s < 4; s++) {
        vf0[s] = *(const s8*)(vc + 1024 * s);
        vf1[s] = *(const s8*)(vc + 1024 * s + 512);
      }
    }
    const char* Ks = (const char*)&lds[buf][0];

    // QK^T swapped: st[k][q], A = K rows, B = Q frags
    f16v st0 = {}, st1 = {};
    __builtin_amdgcn_s_setprio(1);
#pragma unroll
    for (int t = 0; t < 4; t++) {
      int off = (32 * t + 16 * h) ^ swz;
      s8 a0 = *(const s8*)(Ks + q32 * 128 + off);
      s8 a1 = *(const s8*)(Ks + (32 + q32) * 128 + off);
      st0 = MFMA32(a0, qf[t], st0);
      st1 = MFMA32(a1, qf[t], st1);
    }
    __builtin_amdgcn_s_setprio(0);

    if (tail) {                        // tail: only kv=1024 (reg0,h=0,tile0) valid
      st0[0] = h ? -3e38f : st0[0];
#pragma unroll
      for (int r = 1; r < 16; r++) st0[r] = -3e38f;
#pragma unroll
      for (int r = 0; r < 16; r++) st1[r] = -3e38f;
    }

    // exp (no max subtraction) + tree sum
    float sm[8];
#pragma unroll
    for (int r = 0; r < 16; r++) {
      st0[r] = exp2f_(st0[r]);
      st1[r] = exp2f_(st1[r]);
    }
#pragma unroll
    for (int r = 0; r < 8; r++) sm[r] = (st0[r] + st0[r + 8]) + (st1[r] + st1[r + 8]);
#pragma unroll
    for (int w = 4; w >= 1; w >>= 1)
#pragma unroll
      for (int r = 0; r < w; r++) sm[r] += sm[r + w];
    lrun += sm[0] + __shfl_xor(sm[0], 32);

    // PV: A = P (slot j <-> kv = 4h+(j&3)+8(j>>2), same map as Vp's m)
    __builtin_amdgcn_s_setprio(1);
#pragma unroll
    for (int s = 0; s < 4; s++) {
      union { s8 v; u32 w[4]; } pa;
#pragma unroll
      for (int i = 0; i < 4; i++) {
        float plo = (s < 2) ? st0[8 * (s & 1) + 2 * i]     : st1[8 * (s & 1) + 2 * i];
        float phi = (s < 2) ? st0[8 * (s & 1) + 2 * i + 1] : st1[8 * (s & 1) + 2 * i + 1];
        pa.w[i] = cvtpk(plo, phi);
      }
      o0 = MFMA32(pa.v, vf0[s], o0);
      o1 = MFMA32(pa.v, vf1[s], o1);
    }
    __builtin_amdgcn_s_setprio(0);
  };

  // prologue: stage pair 0 (chunks 0,1) into bufs 0,1
  stage(0, 0);
  stage(1, 1);
  __syncthreads();

  for (int p = 0; p < 8; p++) {        // 8 pairs cover chunks 0..15
    int base = (p & 1) << 1;           // bufs {base, base+1} hold this pair
    int nbase = base ^ 2;              // stage next pair (or tail) into the other two
    if (p < 7) {
      stage(nbase,     2 * p + 2);
      stage(nbase + 1, 2 * p + 3);
    } else {
      stage(nbase, 16);                // p=7: base=2, nbase=0 -> chunk 16 into buf 0
    }
    body(2 * p,     base,     false);
    body(2 * p + 1, base + 1, false);
    __syncthreads();                   // drains next-pair gloads + this pair's ds_reads
  }
  body(16, 0, true);                   // tail chunk lives in buf 0

  float rl = 1.0f / lrun;
#pragma unroll
  for (int r = 0; r < 16; r++) {
    int cr = (r & 3) + 8 * (r >> 2) + 4 * h;
    float sc = __shfl(rl, cr);
    u16* dst = Ao + (size_t)(b * SEQ + qb + cr) * DIM + hh * HD;
    dst[q32]      = f2bf(o0[r] * sc);
    dst[32 + q32] = f2bf(o1[r] * sc);
  }
}

extern "C" void kernel_launch(void* const* d_in, const int* in_sizes, int n_in,
                              void* d_out, int out_size, void* d_ws, size_t ws_size,
                              hipStream_t stream) {
  const float* x  = (const float*)d_in[0];
  const float* qw = (const float*)d_in[1];
  const float* qb = (const float*)d_in[2];
  const float* kw = (const float*)d_in[3];
  const float* vw = (const float*)d_in[4];
  const float* vb = (const float*)d_in[5];
  const float* ow = (const float*)d_in[6];
  const float* ob = (const float*)d_in[7];
  float* out = (float*)d_out;

  char* ws = (char*)d_ws;
  u16*    xb   = (u16*)(ws);                  // 12,779,520 B (8320*768*2), batch-padded
  u16*    wqkv = (u16*)(ws + 12779520);       //  3,538,944
  u16*    wo   = (u16*)(ws + 16318464);       //  1,179,648
  float*  bq   = (float*)(ws + 17498112);     //      9,216
  float2* rt   = (float2*)(ws + 17507328);    //    262,400 (1025*32*8)
  u16*    Ql   = (u16*)(ws + 17769728);       // 12,779,520 (96*1040*64*2)
  u16*    Kl   = (u16*)(ws + 30549248);       // 13,369,344 (96*1088*64*2)
  u16*    Vp   = (u16*)(ws + 43918592);       // 13,369,344 (96*68*64*16*2)
  u16*    Ao   = xb;                          // alias: xb dead after gemm1

  conv_all<<<8544, 256, 0, stream>>>(x, qw, kw, vw, ow, qb, vb, xb, wqkv, wo, bq, rt);
  gemm_qkv<<<585, 512, 0, stream>>>(xb, wqkv, bq, Ql, Kl, Vp, rt);
  attn_k<<<dim3(96, 9), 256, 0, stream>>>(Ql, Kl, Vp, Ao);
  gemm_o<<<390, 256, 0, stream>>>(Ao, wo, out, ob, DIM, DIM, MV, 6);
}

// Round 21
// 140.371 us; speedup vs baseline: 1.1242x; 1.1242x over previous
//
#include <hip/hip_runtime.h>

typedef unsigned short u16;
typedef unsigned int   u32;
typedef __attribute__((ext_vector_type(4))) short s4;
typedef __attribute__((ext_vector_type(8))) short s8;
typedef __attribute__((ext_vector_type(4))) float f4;
typedef __attribute__((ext_vector_type(16))) float f16v;

#define NB   8
#define SEQ  1025
#define DIM  768
#define NH   12
#define HD   64
#define BPAD 1040      // rows per batch, padded (65*16)
#define MPAD 8320      // 8*1040
#define MV   8200      // valid rows for gemm2
#define SQP  1040      // Q rows per (b,h)
#define SKP  1088      // K rows per (b,h): 17*64
#define NG16 68        // kv 16-groups per (b,h)
#define NQKV 2304
#define BHT  96
// hd^-0.5 * log2(e) folded into Q (softmax uses exp2)
#define QSCALE 0.1803368801111204f

__device__ __forceinline__ u16 f2bf(float f) {
  u32 u = __builtin_bit_cast(u32, f);
  u += 0x7fffu + ((u >> 16) & 1u);
  return (u16)(u >> 16);
}
__device__ __forceinline__ float bf2f(u16 h) {
  return __builtin_bit_cast(float, ((u32)h) << 16);
}
__device__ __forceinline__ float exp2f_(float x) {
#if __has_builtin(__builtin_amdgcn_exp2f)
  return __builtin_amdgcn_exp2f(x);
#else
  return exp2f(x);
#endif
}
__device__ __forceinline__ u32 cvtpk(float a, float b) {
  u32 r;
  asm("v_cvt_pk_bf16_f32 %0, %1, %2" : "=v"(r) : "v"(a), "v"(b));
  return r;
}

typedef const __attribute__((address_space(1))) void cas1v;
typedef __attribute__((address_space(3))) void as3v;
__device__ __forceinline__ void gload16(const void* g, void* l) {
  __builtin_amdgcn_global_load_lds((cas1v*)g, (as3v*)l, 16, 0, 0);
}

#define MFMA16(a, b, c) __builtin_amdgcn_mfma_f32_16x16x32_bf16(a, b, c, 0, 0, 0)
#define MFMA32(a, b, c) __builtin_amdgcn_mfma_f32_32x32x16_bf16(a, b, c, 0, 0, 0)

// ---- fused conversions: x (batch-padded bf16), weights, qkv bias, RoPE table ----
__global__ void conv_all(const float* __restrict__ x,
                         const float* __restrict__ qw, const float* __restrict__ kw,
                         const float* __restrict__ vw, const float* __restrict__ ow,
                         const float* __restrict__ qb, const float* __restrict__ vb,
                         u16* __restrict__ xb,
                         u16* __restrict__ wqkv, u16* __restrict__ wo,
                         float* __restrict__ biasq, float2* __restrict__ rt) {
  if (blockIdx.x < 6240) {                        // ---- x part: 8320*768/4 elems ----
    int i = blockIdx.x * 256 + threadIdx.x;
    int e = i * 4;
    int row = e / DIM, col = e - row * DIM;
    int b = row / BPAD, s = row - b * BPAD;
    s4 o;
    if (s < SEQ) {
      float4 v = *(const float4*)(x + ((size_t)(b * SEQ + s)) * DIM + col);
      o[0] = (short)f2bf(v.x); o[1] = (short)f2bf(v.y);
      o[2] = (short)f2bf(v.z); o[3] = (short)f2bf(v.w);
    } else {
      o = (s4){0, 0, 0, 0};
    }
    *(s4*)(xb + e) = o;
  } else {                                        // ---- weights part: 589,824 elems ----
    int i = (blockIdx.x - 6240) * 256 + threadIdx.x;
    wqkv[i]           = f2bf(qw[i]);
    wqkv[i + 589824]  = f2bf(kw[i]);
    wqkv[i + 1179648] = f2bf(vw[i]);
    wo[i]             = f2bf(ow[i]);
    if (i < NQKV) biasq[i] = (i < 768) ? qb[i] : (i < 1536 ? 0.f : vb[i - 1536]);
    if (i < SEQ * 32) {                           // rope table rt[s][jj]
      int s = i >> 5, jj = i & 31;
      float cs = 1.f, sn = 0.f;
      if (s > 0) {
        int tok = s - 1;
        int pos = (jj < 16) ? (tok >> 5) : (tok & 31);
        int f = jj & 15;
        float ang = (float)pos * __expf((float)f * -0.28782313662425572f); // 100^(-f/16)
        __sincosf(ang, &sn, &cs);
      }
      rt[i] = make_float2(cs, sn);
    }
  }
}

// ======== gemm_qkv: 128m x 256n tile, BK=32, 2-phase dbuf, 512 thr, LDS 48KB ========
// 8 waves = 2m x 4n, 64x64 each (acc[4][4]). Epilogue streams through a 64x258 C-tile
// (33KB, aliased in the staging region) in TWO halves.
__global__ __launch_bounds__(512, 4) void gemm_qkv(const u16* __restrict__ A, const u16* __restrict__ Bm,
                                                   const float* __restrict__ bias,
                                                   u16* __restrict__ Ql, u16* __restrict__ Kl,
                                                   u16* __restrict__ Vp, const float2* __restrict__ rt) {
  __shared__ u16 smem[24576];            // staging: A 2x4096 + B 2x8192 = 24576 u16 = 48KB
  const int K = DIM;
  int tid = threadIdx.x;
  int lane = tid & 63, wave = tid >> 6;
  int g = lane >> 4, c16 = lane & 15;
  int wm = wave >> 2, wn = wave & 3;
  // bijective XCD swizzle (m204), n fastest
  int nwg = gridDim.x, orig = blockIdx.x;
  int qd = nwg >> 3, rm = nwg & 7, xcd = orig & 7;
  int wgid = (xcd < rm ? xcd * (qd + 1) : rm * (qd + 1) + (xcd - rm) * qd) + (orig >> 3);
  int m0 = (wgid / 9) * 128, n0 = (wgid % 9) * 256;
  f4 acc[4][4] = {};

  int ldrow = wave * 16 + (lane >> 2);               // 0..127
  int ldk = ((lane & 3) ^ ((ldrow >> 1) & 3)) * 8;   // inverse chunk swizzle on global source
  const u16* Asrc = A + (size_t)(m0 + ldrow) * K + ldk;
  const u16* Bsrc = Bm + (size_t)(n0 + ldrow) * K + ldk;

  auto stage = [&](int buf, int k0) {
    gload16(Asrc + k0,           smem + buf * 4096 + wave * 512);          // A 128x32
    gload16(Bsrc + k0,           smem + 8192 + buf * 8192 + wave * 512);   // B rows 0..127
    gload16(Bsrc + 128 * K + k0, smem + 8192 + buf * 8192 + 4096 + wave * 512); // B rows 128..255
  };

  stage(0, 0);
  __syncthreads();
  int kx = (g ^ ((c16 >> 1) & 3)) * 8;               // swizzled read chunk
  for (int t = 0; t < 24; t++) {
    int buf = t & 1;
    if (t + 1 < 24) stage(buf ^ 1, (t + 1) << 5);
    s8 af[4], bf[4];
#pragma unroll
    for (int i = 0; i < 4; i++) {
      af[i] = *(const s8*)(smem + buf * 4096 + (wm * 64 + i * 16 + c16) * 32 + kx);
      bf[i] = *(const s8*)(smem + 8192 + buf * 8192 + (wn * 64 + i * 16 + c16) * 32 + kx);
    }
    __builtin_amdgcn_s_setprio(1);
#pragma unroll
    for (int i = 0; i < 4; i++)
#pragma unroll
      for (int j = 0; j < 4; j++)
        acc[i][j] = MFMA16(af[i], bf[j], acc[i][j]);
    __builtin_amdgcn_s_setprio(0);
    __syncthreads();
  }

  // ======== epilogue: two 64-row halves through a 64x258 C-tile (33KB, aliases staging) ====
  int part = (n0 >= 1536) ? 2 : (n0 >= 768 ? 1 : 0);   // 256-blocks are part-pure
  float qs = (part == 0) ? QSCALE : 1.0f;
  u16 (*ct)[258] = (u16(*)[258])smem;
#pragma unroll
  for (int ih = 0; ih < 2; ih++) {
    __syncthreads();                     // prior reads of ct/staging complete
#pragma unroll
    for (int j = 0; j < 4; j++) {
      int col = wn * 64 + j * 16 + c16;                // 0..255
      float bv = bias[n0 + col];
      int jj = (col & 63) >> 1;
      int odd = col & 1;
#pragma unroll
      for (int il = 0; il < 2; il++) {
        int i = ih * 2 + il;
        int lrow = wm * 32 + il * 16 + g * 4;          // local C-tile row base
        int mrow = m0 + wm * 64 + i * 16 + g * 4;      // global m base
#pragma unroll
        for (int r = 0; r < 4; r++) {
          float v = acc[i][j][r] + bv;
          u16 o;
          if (part < 2) {
            float vp = __shfl_xor(v, 1);
            int s = (mrow + r) % BPAD;
            float2 t = rt[(s < SEQ ? s : SEQ - 1) * 32 + jj];
            float rv = odd ? (v * t.x + vp * t.y) : (v * t.x - vp * t.y);
            o = f2bf(rv * qs);
          } else {
            o = f2bf(v);
          }
          ct[lrow + r][col] = o;
        }
      }
    }
    __syncthreads();
    if (part < 2) {
      u16* dstB = (part == 0) ? Ql : Kl;
      int stride = (part == 0) ? SQP : SKP;
#pragma unroll
      for (int p = 0; p < 4; p++) {
        int task = p * 512 + tid;        // 2048 tasks: 64 rows x 32 col-groups
        int lrow = task >> 5, cg = (task & 31) * 8;
        int m = m0 + (lrow >> 5) * 64 + ih * 32 + (lrow & 31);
        int b = m / BPAD, s = m - b * BPAD;
        int n = n0 + cg;
        int hq = (n >> 6) - part * NH;
        s8 v = *(const s8*)&ct[lrow][cg];
        *(s8*)(dstB + ((size_t)((b * NH + hq) * stride + s)) * HD + (n & 63)) = v;
      }
    } else {
#pragma unroll
      for (int p = 0; p < 2; p++) {
        int task = p * 512 + tid;        // 1024 tasks: 4 strips x 256 cols
        int col = task & 255, rg = task >> 8;
        int lbase = rg * 16;
        int mb = m0 + (lbase >> 5) * 64 + ih * 32 + (lbase & 31);
        int b = mb / BPAD, sb = mb - b * BPAD;
        int g16 = sb >> 4;               // 16-strip aligned, batch-pure (1040 % 16 == 0)
        int n = n0 + col;
        int hq = (n >> 6) - 2 * NH;
        s8 o0, o1;
#pragma unroll
        for (int k = 0; k < 16; k++) {
          int mp = (k & 3) | (((k >> 3) & 1) << 2) | (((k >> 2) & 1) << 3);
          u16 val = ct[lbase + k][col];
          if (mp < 8) o0[mp] = (short)val; else o1[mp - 8] = (short)val;
        }
        u16* dst = Vp + ((size_t)((b * NH + hq) * NG16 + g16) * HD + (n & 63)) * 16;
        *(s8*)dst = o0;
        *(s8*)(dst + 8) = o1;
      }
    }
  }
}

// ---------------- gemm_o: 128x128 tile, 2-phase dbuf (proven), f32 out + bias ----------------
__global__ __launch_bounds__(256) void gemm_o(const u16* __restrict__ A, const u16* __restrict__ Bm,
                                              float* __restrict__ Cf, const float* __restrict__ bias,
                                              int N, int K, int Mvalid, int nnt) {
  __shared__ u16 smem[16384];
  int tid = threadIdx.x;
  int lane = tid & 63, wave = tid >> 6;
  int g = lane >> 4, c16 = lane & 15;
  int nwg = gridDim.x, orig = blockIdx.x;
  int qd = nwg >> 3, rm = nwg & 7, xcd = orig & 7;
  int wgid = (xcd < rm ? xcd * (qd + 1) : rm * (qd + 1) + (xcd - rm) * qd) + (orig >> 3);
  int m0 = (wgid / nnt) * 128, n0 = (wgid % nnt) * 128;
  int wm = wave >> 1, wn = wave & 1;
  f4 acc[4][4] = {};

  int ldrow = wave * 16 + (lane >> 2);
  int ldk = ((lane & 3) ^ ((ldrow >> 1) & 3)) * 8;
  const u16* Asrc = A + (size_t)(m0 + ldrow) * K + ldk;
  const u16* Bsrc = Bm + (size_t)(n0 + ldrow) * K + ldk;

  auto stage = [&](int buf, int k0) {
    u16* aw = smem + buf * 4096 + wave * 512;
    u16* bw = smem + 8192 + buf * 4096 + wave * 512;
    gload16(Asrc + k0, aw);
    gload16(Asrc + 64 * K + k0, aw + 2048);
    gload16(Bsrc + k0, bw);
    gload16(Bsrc + 64 * K + k0, bw + 2048);
  };

  stage(0, 0);
  __syncthreads();
  int nk = K >> 5;
  int kx = (g ^ ((c16 >> 1) & 3)) * 8;
  for (int t = 0; t < nk; t++) {
    int buf = t & 1;
    if (t + 1 < nk) stage(buf ^ 1, (t + 1) << 5);
    s8 af[4], bf[4];
#pragma unroll
    for (int i = 0; i < 4; i++) {
      af[i] = *(const s8*)(smem + buf * 4096 + (wm * 64 + i * 16 + c16) * 32 + kx);
      bf[i] = *(const s8*)(smem + 8192 + buf * 4096 + (wn * 64 + i * 16 + c16) * 32 + kx);
    }
    __builtin_amdgcn_s_setprio(1);
#pragma unroll
    for (int i = 0; i < 4; i++)
#pragma unroll
      for (int j = 0; j < 4; j++)
        acc[i][j] = MFMA16(af[i], bf[j], acc[i][j]);
    __builtin_amdgcn_s_setprio(0);
    __syncthreads();
  }

#pragma unroll
  for (int i = 0; i < 4; i++)
#pragma unroll
    for (int j = 0; j < 4; j++) {
      int n = n0 + wn * 64 + j * 16 + c16;
      float bv = bias[n];
#pragma unroll
      for (int r = 0; r < 4; r++) {
        int m = m0 + wm * 64 + i * 16 + g * 4 + r;
        if (m < Mvalid) Cf[(size_t)m * N + n] = acc[i][j][r] + bv;
      }
    }
}

// ---------------- flash attention: 4 waves x 32 q-rows, KVBLK=64, PAIRED chunks ----------------
// K staged to LDS (XOR swizzle) with FOUR buffers: stage a PAIR of chunks, compute a pair,
// ONE __syncthreads per pair -> 9 barrier/drain events instead of 17. Tail chunk 16 is
// staged into buf 0 at p=7 and read from buf 0. V direct from global (Vp pre-permuted,
// coalesced b128). NO-MAX softmax (bounded scores).
__global__ __launch_bounds__(256) void attn_k(const u16* __restrict__ Q, const u16* __restrict__ K,
                                              const u16* __restrict__ Vp, u16* __restrict__ Ao) {
  __shared__ u16 lds[4][64 * 64];      // 4 x 8 KiB K tiles = 32 KiB
  int bh = blockIdx.x;
  int tid = threadIdx.x;
  int wave = tid >> 6, lane = tid & 63;
  int q32 = lane & 31, h = lane >> 5;
  int b = bh / NH, hh = bh % NH;
  int qb = blockIdx.y * 128 + wave * 32;
  if (qb > SEQ - 32) qb = SEQ - 32;    // tail waves recompute rows (identical writes)
  const u16* Qb = Q + (size_t)bh * SQP * HD;
  const u16* Kb = K + (size_t)bh * SKP * HD;
  const u16* Vb = Vp + (size_t)bh * NG16 * 1024 + 16 * q32 + 8 * h;  // lane-fixed offset

  s8 qf[4];
#pragma unroll
  for (int t = 0; t < 4; t++)
    qf[t] = *(const s8*)(Qb + (size_t)(qb + q32) * HD + 16 * t + 8 * h);

  f16v o0 = {}, o1 = {};
  float lrun = 0.f;
  int swz = (q32 & 7) << 4;

  auto stage = [&](int buf, int c) {   // K only: 2 x gload16 per thread
#pragma unroll
    for (int i = 0; i < 2; i++) {
      int sb = i * 4096 + tid * 16;
      int row = sb >> 7;
      int ch = (sb >> 4) & 7;
      int so = (ch ^ (row & 7)) * 8;
      u16* kd = &lds[buf][i * 2048 + wave * 512];
      gload16(Kb + (size_t)(c * 64 + row) * HD + so, kd);
    }
  };

  auto body = [&](int c, int buf, bool tail) {
    // V fragments: direct global b128, issued first (hidden under QK + softmax)
    s8 vf0[4], vf1[4];
    {
      const u16* vc = Vb + c * 4096;
#pragma unroll
      for (int s = 0; s < 4; s++) {
        vf0[s] = *(const s8*)(vc + 1024 * s);
        vf1[s] = *(const s8*)(vc + 1024 * s + 512);
      }
    }
    const char* Ks = (const char*)&lds[buf][0];

    // QK^T swapped: st[k][q], A = K rows, B = Q frags
    f16v st0 = {}, st1 = {};
    __builtin_amdgcn_s_setprio(1);
#pragma unroll
    for (int t = 0; t < 4; t++) {
      int off = (32 * t + 16 * h) ^ swz;
      s8 a0 = *(const s8*)(Ks + q32 * 128 + off);
      s8 a1 = *(const s8*)(Ks + (32 + q32) * 128 + off);
      st0 = MFMA32(a0, qf[t], st0);
      st1 = MFMA32(a1, qf[t], st1);
    }
    __builtin_amdgcn_s_setprio(0);

    if (tail) {                        // tail: only kv=1024 (reg0,h=0,tile0) valid
      st0[0] = h ? -3e38f : st0[0];
#pragma unroll
      for (int r = 1; r < 16; r++) st0[r] = -3e38f;
#pragma unroll
      for (int r = 0; r < 16; r++) st1[r] = -3e38f;
    }

    // exp (no max subtraction) + tree sum
    float sm[8];
#pragma unroll
    for (int r = 0; r < 16; r++) {
      st0[r] = exp2f_(st0[r]);
      st1[r] = exp2f_(st1[r]);
    }
#pragma unroll
    for (int r = 0; r < 8; r++) sm[r] = (st0[r] + st0[r + 8]) + (st1[r] + st1[r + 8]);
#pragma unroll
    for (int w = 4; w >= 1; w >>= 1)
#pragma unroll
      for (int r = 0; r < w; r++) sm[r] += sm[r + w];
    lrun += sm[0] + __shfl_xor(sm[0], 32);

    // PV: A = P (slot j <-> kv = 4h+(j&3)+8(j>>2), same map as Vp's m)
    __builtin_amdgcn_s_setprio(1);
#pragma unroll
    for (int s = 0; s < 4; s++) {
      union { s8 v; u32 w[4]; } pa;
#pragma unroll
      for (int i = 0; i < 4; i++) {
        float plo = (s < 2) ? st0[8 * (s & 1) + 2 * i]     : st1[8 * (s & 1) + 2 * i];
        float phi = (s < 2) ? st0[8 * (s & 1) + 2 * i + 1] : st1[8 * (s & 1) + 2 * i + 1];
        pa.w[i] = cvtpk(plo, phi);
      }
      o0 = MFMA32(pa.v, vf0[s], o0);
      o1 = MFMA32(pa.v, vf1[s], o1);
    }
    __builtin_amdgcn_s_setprio(0);
  };

  // prologue: stage pair 0 (chunks 0,1) into bufs 0,1
  stage(0, 0);
  stage(1, 1);
  __syncthreads();

  for (int p = 0; p < 8; p++) {        // 8 pairs cover chunks 0..15
    int base = (p & 1) << 1;           // bufs {base, base+1} hold this pair
    int nbase = base ^ 2;              // stage next pair (or tail) into the other two
    if (p < 7) {
      stage(nbase,     2 * p + 2);
      stage(nbase + 1, 2 * p + 3);
    } else {
      stage(nbase, 16);                // p=7: base=2, nbase=0 -> chunk 16 into buf 0
    }
    body(2 * p,     base,     false);
    body(2 * p + 1, base + 1, false);
    __syncthreads();                   // drains next-pair gloads + this pair's ds_reads
  }
  body(16, 0, true);                   // tail chunk lives in buf 0

  float rl = 1.0f / lrun;
#pragma unroll
  for (int r = 0; r < 16; r++) {
    int cr = (r & 3) + 8 * (r >> 2) + 4 * h;
    float sc = __shfl(rl, cr);
    u16* dst = Ao + (size_t)(b * SEQ + qb + cr) * DIM + hh * HD;
    dst[q32]      = f2bf(o0[r] * sc);
    dst[32 + q32] = f2bf(o1[r] * sc);
  }
}

extern "C" void kernel_launch(void* const* d_in, const int* in_sizes, int n_in,
                              void* d_out, int out_size, void* d_ws, size_t ws_size,
                              hipStream_t stream) {
  const float* x  = (const float*)d_in[0];
  const float* qw = (const float*)d_in[1];
  const float* qb = (const float*)d_in[2];
  const float* kw = (const float*)d_in[3];
  const float* vw = (const float*)d_in[4];
  const float* vb = (const float*)d_in[5];
  const float* ow = (const float*)d_in[6];
  const float* ob = (const float*)d_in[7];
  float* out = (float*)d_out;

  char* ws = (char*)d_ws;
  u16*    xb   = (u16*)(ws);                  // 12,779,520 B (8320*768*2), batch-padded
  u16*    wqkv = (u16*)(ws + 12779520);       //  3,538,944
  u16*    wo   = (u16*)(ws + 16318464);       //  1,179,648
  float*  bq   = (float*)(ws + 17498112);     //      9,216
  float2* rt   = (float2*)(ws + 17507328);    //    262,400 (1025*32*8)
  u16*    Ql   = (u16*)(ws + 17769728);       // 12,779,520 (96*1040*64*2)
  u16*    Kl   = (u16*)(ws + 30549248);       // 13,369,344 (96*1088*64*2)
  u16*    Vp   = (u16*)(ws + 43918592);       // 13,369,344 (96*68*64*16*2)
  u16*    Ao   = xb;                          // alias: xb dead after gemm1

  conv_all<<<8544, 256, 0, stream>>>(x, qw, kw, vw, ow, qb, vb, xb, wqkv, wo, bq, rt);
  gemm_qkv<<<585, 512, 0, stream>>>(xb, wqkv, bq, Ql, Kl, Vp, rt);
  attn_k<<<dim3(96, 9), 256, 0, stream>>>(Ql, Kl, Vp, Ao);
  gemm_o<<<390, 256, 0, stream>>>(Ao, wo, out, ob, DIM, DIM, MV, 6);
}